// Round 5
// baseline (565.641 us; speedup 1.0000x reference)
//
#include <hip/hip_runtime.h>
#include <hip/hip_bf16.h>

#define SEQ 4096
#define HIDDEN 1280
#define NH 16
#define HD 80
#define QKV_N 3840
#define INV_SCALE 0.11180339887498949f
#define LOG2E 1.4426950408889634f

typedef __attribute__((ext_vector_type(8))) short bf16x8;
typedef __attribute__((ext_vector_type(4))) float f32x4;

__device__ __forceinline__ ushort f2bf(float f) {
  union { float f; unsigned u; } v; v.f = f;
  unsigned u = v.u;
  u += 0x7fff + ((u >> 16) & 1);   // RTNE
  return (ushort)(u >> 16);
}
__device__ __forceinline__ float bf2f(ushort h) {
  union { unsigned u; float f; } v; v.u = ((unsigned)h) << 16;
  return v.f;
}
__device__ __forceinline__ unsigned pk_bf16(float a, float b) {
  union { __hip_bfloat162 h; unsigned u; } v;
  v.h = __float22bfloat162_rn(make_float2(a, b));
  return v.u;
}
// async global->LDS, 16B per lane. LDS side must be base + lane*16 contiguous.
__device__ __forceinline__ void async16(void* lds, const void* g) {
  __builtin_amdgcn_global_load_lds(
      (const __attribute__((address_space(1))) unsigned*)g,
      (__attribute__((address_space(3))) unsigned*)(unsigned)(size_t)lds,
      16, 0, 0);
}

// ---------------- split fp32 -> bf16 hi/lo, elementwise ----------------
__global__ __launch_bounds__(256)
void split_rows(const float* __restrict__ A, ushort* __restrict__ hi,
                ushort* __restrict__ lo, int n) {
  int i = (blockIdx.x * 256 + threadIdx.x) * 4;
  if (i >= n) return;
  float4 v = *(const float4*)&A[i];
  ushort h[4], l[4];
  float x[4] = {v.x, v.y, v.z, v.w};
#pragma unroll
  for (int t = 0; t < 4; ++t) {
    h[t] = f2bf(x[t]);
    l[t] = f2bf(x[t] - bf2f(h[t]));
  }
  *(ushort4*)&hi[i] = *(ushort4*)h;
  *(ushort4*)&lo[i] = *(ushort4*)l;
}

// ------------- split + transpose: W[K][N] -> hiT/loT [N][K] -------------
__global__ __launch_bounds__(256)
void split_T(const float* __restrict__ W, ushort* __restrict__ hiT,
             ushort* __restrict__ loT, int K, int N) {
  __shared__ float T[32][33];
  const int k0 = blockIdx.y * 32, n0 = blockIdx.x * 32;
  for (int e = threadIdx.x; e < 1024; e += 256) {
    int r = e >> 5, c = e & 31;
    T[r][c] = W[(size_t)(k0 + r) * N + n0 + c];
  }
  __syncthreads();
  for (int e = threadIdx.x; e < 1024; e += 256) {
    int r = e >> 5, c = e & 31;        // r: n-index, c: k-index
    float x = T[c][r];
    ushort h = f2bf(x);
    ushort l = f2bf(x - bf2f(h));
    size_t idx = (size_t)(n0 + r) * K + k0 + c;
    hiT[idx] = h; loT[idx] = l;
  }
}

// ------- split-bf16 GEMM: C[M,N] = (Ah+Al)[M,K] @ (Bh+Bl)^T[N,K] + bias -------
// 128x128 tile, BK=32, 4 waves (each 64x64), 3 MFMA per frag pair (drop lo*lo).
__global__ __launch_bounds__(256)
void gemm_bt_split(const ushort* __restrict__ Ah, const ushort* __restrict__ Al,
                   const ushort* __restrict__ Bh, const ushort* __restrict__ Bl,
                   const float* __restrict__ bias, float* __restrict__ C,
                   int M, int N, int K) {
  __shared__ __align__(16) ushort lds[16384];   // Ah|Al|Bh|Bl tiles, 8KB each
  const int tid = threadIdx.x, lane = tid & 63, w = tid >> 6;
  const int m15 = lane & 15, g = lane >> 4;
  const int m0 = blockIdx.y * 128, n0 = blockIdx.x * 128;
  const int wm = (w & 1) * 64, wn = (w >> 1) * 64;

  const ushort* stage_base =
      (w == 0) ? Ah + (size_t)m0 * K :
      (w == 1) ? Al + (size_t)m0 * K :
      (w == 2) ? Bh + (size_t)n0 * K : Bl + (size_t)n0 * K;
  char* ldsb = (char*)lds;

  f32x4 acc[4][4];
#pragma unroll
  for (int i = 0; i < 4; ++i)
#pragma unroll
    for (int j = 0; j < 4; ++j) acc[i][j] = (f32x4){0.f, 0.f, 0.f, 0.f};

  for (int k0 = 0; k0 < K; k0 += 32) {
    __syncthreads();
#pragma unroll
    for (int i = 0; i < 8; ++i) {
      int o = i * 1024 + lane * 16;      // byte offset within 8KB region
      int row = o >> 6, colb = o & 63;   // 64 B per row (32 bf16)
      async16(ldsb + w * 8192 + o,
              (const char*)(stage_base + (size_t)row * K + k0) + colb);
    }
    __syncthreads();
    bf16x8 ah[4], al[4], bh[4], bl[4];
#pragma unroll
    for (int t = 0; t < 4; ++t) {
      ah[t] = *(const bf16x8*)&lds[(wm + t * 16 + m15) * 32 + g * 8];
      al[t] = *(const bf16x8*)&lds[4096 + (wm + t * 16 + m15) * 32 + g * 8];
      bh[t] = *(const bf16x8*)&lds[8192 + (wn + t * 16 + m15) * 32 + g * 8];
      bl[t] = *(const bf16x8*)&lds[12288 + (wn + t * 16 + m15) * 32 + g * 8];
    }
#pragma unroll
    for (int mi = 0; mi < 4; ++mi)
#pragma unroll
      for (int ni = 0; ni < 4; ++ni) {
        acc[mi][ni] = __builtin_amdgcn_mfma_f32_16x16x32_bf16(ah[mi], bh[ni], acc[mi][ni], 0, 0, 0);
        acc[mi][ni] = __builtin_amdgcn_mfma_f32_16x16x32_bf16(ah[mi], bl[ni], acc[mi][ni], 0, 0, 0);
        acc[mi][ni] = __builtin_amdgcn_mfma_f32_16x16x32_bf16(al[mi], bh[ni], acc[mi][ni], 0, 0, 0);
      }
  }
#pragma unroll
  for (int mi = 0; mi < 4; ++mi)
#pragma unroll
    for (int ni = 0; ni < 4; ++ni) {
      int col = n0 + wn + ni * 16 + m15;
      float bv = bias[col];
#pragma unroll
      for (int r = 0; r < 4; ++r)
        C[(size_t)(m0 + wm + mi * 16 + g * 4 + r) * N + col] = acc[mi][ni][r] + bv;
    }
}

// ------------- rotary + cast: Qb/Kb [h][s][96] (zero-padded) -------------
__global__ __launch_bounds__(256)
void rotary_qk(const float* __restrict__ qkv, const float* __restrict__ cosb,
               const float* __restrict__ sinb, ushort* __restrict__ Qb,
               ushort* __restrict__ Kb) {
  int id = blockIdx.x * 256 + threadIdx.x;
  int j = id % 48;
  int h = (id / 48) % NH;
  int s = id / (48 * NH);
  size_t qrow = (size_t)((h << 12) + s) * 96;
  if (j < 40) {
    size_t base = (size_t)s * QKV_N + h * HD;
    float c1 = cosb[s * HD + j],      s1 = sinb[s * HD + j];
    float c2 = cosb[s * HD + j + 40], s2 = sinb[s * HD + j + 40];
    const float QS = INV_SCALE * LOG2E;
    float q1 = qkv[base + j], q2 = qkv[base + j + 40];
    Qb[qrow + j]      = f2bf((q1 * c1 - q2 * s1) * QS);
    Qb[qrow + j + 40] = f2bf((q2 * c2 + q1 * s2) * QS);
    float k1 = qkv[base + HIDDEN + j], k2 = qkv[base + HIDDEN + j + 40];
    Kb[qrow + j]      = f2bf(k1 * c1 - k2 * s1);
    Kb[qrow + j + 40] = f2bf(k2 * c2 + k1 * s2);
  } else {
    int d = 80 + (j - 40) * 2;
    Qb[qrow + d] = 0; Qb[qrow + d + 1] = 0;
    Kb[qrow + d] = 0; Kb[qrow + d + 1] = 0;
  }
}

// ------------- V transpose: qkv v-section -> VbT[h][80][4096] bf16 -------------
__global__ __launch_bounds__(256)
void v_trans(const float* __restrict__ qkv, ushort* __restrict__ VbT) {
  __shared__ float T[64][81];
  const int h = blockIdx.y, s0 = blockIdx.x * 64;
  for (int e = threadIdx.x; e < 5120; e += 256) {
    int r = e / 80, d = e % 80;
    T[r][d] = qkv[(size_t)(s0 + r) * QKV_N + 2 * HIDDEN + h * HD + d];
  }
  __syncthreads();
  for (int e = threadIdx.x; e < 2560; e += 256) {
    int d = e >> 5, rp = (e & 31) * 2;
    ushort2 p;
    p.x = f2bf(T[rp][d]);
    p.y = f2bf(T[rp + 1][d]);
    *(ushort2*)&VbT[(size_t)h * 80 * SEQ + (size_t)d * SEQ + s0 + rp] = p;
  }
}

// -------- flash attention, bf16 MFMA, fixed-max softmax, barrier-free --------
// grid (SEQ/128, NH, 2): 1024 blocks, 4 waves x 32 q-rows; each block does half
// the key range. K/V fragments loaded DIRECTLY global->VGPR (L2-resident,
// per-lane 16B contiguous); only the P C->A transform goes through LDS
// (wave-private rows, lgkmcnt only -- no __syncthreads anywhere).
// Emits unnormalized O (fp32) + l partials; merge_split combines halves.
#define LPS 88    // Ps row stride (ushort)
__global__ __launch_bounds__(256)
void attn_mfma(const ushort* __restrict__ Qb, const ushort* __restrict__ Kb,
               const ushort* __restrict__ VbT, float* __restrict__ Op,
               float* __restrict__ lp) {
  __shared__ __align__(16) ushort Ps[128 * LPS];   // 22.5 KB

  const int tid = threadIdx.x, lane = tid & 63, w = tid >> 6;
  const int m15 = lane & 15, g = lane >> 4;
  const int h = blockIdx.y, q0 = blockIdx.x * 128, half = blockIdx.z;
  const ushort* Qh = Qb + (size_t)h * SEQ * 96;
  const ushort* Kh = Kb + (size_t)h * SEQ * 96;
  const ushort* Vh = VbT + (size_t)h * 80 * SEQ;

  // ---- Q fragments straight from global (persistent)
  bf16x8 qf[2][3];
#pragma unroll
  for (int mi = 0; mi < 2; ++mi)
#pragma unroll
    for (int c = 0; c < 3; ++c)
      qf[mi][c] = *(const bf16x8*)&Qh[(size_t)(q0 + w * 32 + mi * 16 + m15) * 96 + c * 32 + g * 8];

  f32x4 o_[2][5];
#pragma unroll
  for (int mi = 0; mi < 2; ++mi)
#pragma unroll
    for (int n = 0; n < 5; ++n) o_[mi][n] = (f32x4){0.f, 0.f, 0.f, 0.f};
  float l_part[2] = {0.f, 0.f};

  for (int kt = 0; kt < SEQ / 128; ++kt) {
    const int kbase = half * (SEQ / 2) + kt * 64;
    // ---- S^T = K Q^T per 16-key group; p=exp2(s); pack -> Ps[q][key]
#pragma unroll
    for (int j = 0; j < 4; ++j) {
      const ushort* kr = &Kh[(size_t)(kbase + j * 16 + m15) * 96 + g * 8];
      bf16x8 kf0 = *(const bf16x8*)&kr[0];
      bf16x8 kf1 = *(const bf16x8*)&kr[32];
      bf16x8 kf2 = *(const bf16x8*)&kr[64];
      f32x4 st0 = {0.f, 0.f, 0.f, 0.f}, st1 = {0.f, 0.f, 0.f, 0.f};
      st0 = __builtin_amdgcn_mfma_f32_16x16x32_bf16(kf0, qf[0][0], st0, 0, 0, 0);
      st1 = __builtin_amdgcn_mfma_f32_16x16x32_bf16(kf0, qf[1][0], st1, 0, 0, 0);
      st0 = __builtin_amdgcn_mfma_f32_16x16x32_bf16(kf1, qf[0][1], st0, 0, 0, 0);
      st1 = __builtin_amdgcn_mfma_f32_16x16x32_bf16(kf1, qf[1][1], st1, 0, 0, 0);
      st0 = __builtin_amdgcn_mfma_f32_16x16x32_bf16(kf2, qf[0][2], st0, 0, 0, 0);
      st1 = __builtin_amdgcn_mfma_f32_16x16x32_bf16(kf2, qf[1][2], st1, 0, 0, 0);
      {
        float p0 = __builtin_amdgcn_exp2f(st0[0]);
        float p1 = __builtin_amdgcn_exp2f(st0[1]);
        float p2 = __builtin_amdgcn_exp2f(st0[2]);
        float p3 = __builtin_amdgcn_exp2f(st0[3]);
        l_part[0] += (p0 + p1) + (p2 + p3);
        uint2 pw; pw.x = pk_bf16(p0, p1); pw.y = pk_bf16(p2, p3);
        *(uint2*)&Ps[(w * 32 + m15) * LPS + j * 16 + g * 4] = pw;
      }
      {
        float p0 = __builtin_amdgcn_exp2f(st1[0]);
        float p1 = __builtin_amdgcn_exp2f(st1[1]);
        float p2 = __builtin_amdgcn_exp2f(st1[2]);
        float p3 = __builtin_amdgcn_exp2f(st1[3]);
        l_part[1] += (p0 + p1) + (p2 + p3);
        uint2 pw; pw.x = pk_bf16(p0, p1); pw.y = pk_bf16(p2, p3);
        *(uint2*)&Ps[(w * 32 + 16 + m15) * LPS + j * 16 + g * 4] = pw;
      }
    }
    // ---- V fragments direct from global (issue before the Ps wait)
    bf16x8 vf[2][5];
#pragma unroll
    for (int kc = 0; kc < 2; ++kc)
#pragma unroll
      for (int n = 0; n < 5; ++n)
        vf[kc][n] = *(const bf16x8*)&Vh[(size_t)(n * 16 + m15) * SEQ + kbase + kc * 32 + g * 8];
    // Ps rows are wave-private; order LDS writes before cross-lane reads.
    asm volatile("s_waitcnt lgkmcnt(0)" ::: "memory");
    // ---- O += P V
#pragma unroll
    for (int kc = 0; kc < 2; ++kc) {
      bf16x8 pf0 = *(const bf16x8*)&Ps[(w * 32 + m15) * LPS + kc * 32 + g * 8];
      bf16x8 pf1 = *(const bf16x8*)&Ps[(w * 32 + 16 + m15) * LPS + kc * 32 + g * 8];
#pragma unroll
      for (int n = 0; n < 5; ++n) {
        o_[0][n] = __builtin_amdgcn_mfma_f32_16x16x32_bf16(pf0, vf[kc][n], o_[0][n], 0, 0, 0);
        o_[1][n] = __builtin_amdgcn_mfma_f32_16x16x32_bf16(pf1, vf[kc][n], o_[1][n], 0, 0, 0);
      }
    }
  }
  // ---- l partials: reduce over g-groups; lane m15 holds q=m15's sum
  float l_red[2];
#pragma unroll
  for (int mi = 0; mi < 2; ++mi) {
    float t = l_part[mi];
    t += __shfl_xor(t, 16);
    t += __shfl_xor(t, 32);
    l_red[mi] = t;
  }
  if (g == 0) {
    lp[(size_t)half * SEQ * NH + (size_t)(q0 + w * 32 + m15) * NH + h] = l_red[0];
    lp[(size_t)half * SEQ * NH + (size_t)(q0 + w * 32 + 16 + m15) * NH + h] = l_red[1];
  }
  // ---- unnormalized O partial
  float* Oph = Op + (size_t)half * SEQ * HIDDEN;
#pragma unroll
  for (int mi = 0; mi < 2; ++mi)
#pragma unroll
    for (int r = 0; r < 4; ++r) {
      int grow = q0 + w * 32 + mi * 16 + g * 4 + r;
#pragma unroll
      for (int n = 0; n < 5; ++n)
        Oph[(size_t)grow * HIDDEN + h * HD + n * 16 + m15] = o_[mi][n][r];
    }
}

// -------- merge halves + normalize + split to bf16 hi/lo for proj GEMM --------
__global__ __launch_bounds__(256)
void merge_split(const float* __restrict__ Op, const float* __restrict__ lp,
                 ushort* __restrict__ ao_hi, ushort* __restrict__ ao_lo) {
  int id = blockIdx.x * 256 + threadIdx.x;
  int i4 = id * 4;                          // SEQ*HIDDEN/4 threads
  int s = i4 / HIDDEN, col = i4 % HIDDEN, hh = col / HD;
  float4 a = *(const float4*)&Op[i4];
  float4 b = *(const float4*)&Op[(size_t)SEQ * HIDDEN + i4];
  float l = lp[s * NH + hh] + lp[SEQ * NH + s * NH + hh];
  float inv = 1.f / l;
  float x[4] = {(a.x + b.x) * inv, (a.y + b.y) * inv,
                (a.z + b.z) * inv, (a.w + b.w) * inv};
  ushort h[4], lo[4];
#pragma unroll
  for (int t = 0; t < 4; ++t) {
    h[t] = f2bf(x[t]);
    lo[t] = f2bf(x[t] - bf2f(h[t]));
  }
  *(ushort4*)&ao_hi[i4] = *(ushort4*)h;
  *(ushort4*)&ao_lo[i4] = *(ushort4*)lo;
}

extern "C" void kernel_launch(void* const* d_in, const int* in_sizes, int n_in,
                              void* d_out, int out_size, void* d_ws, size_t ws_size,
                              hipStream_t stream) {
  const float* x      = (const float*)d_in[0];
  const float* cosb   = (const float*)d_in[1];
  const float* sinb   = (const float*)d_in[2];
  const float* w_qkv  = (const float*)d_in[3];
  const float* b_qkv  = (const float*)d_in[4];
  const float* w_proj = (const float*)d_in[5];
  const float* b_proj = (const float*)d_in[6];
  float* out = (float*)d_out;

  // workspace layout (aliased; all kernels strictly ordered on `stream`):
  char* ws = (char*)d_ws;
  float*  qkv   = (float*)ws;                    // 60 MB [0, 62914560); dead after v_trans
  float*  Op    = (float*)ws;                    // 2x4096x1280 f32 = 41,943,040
  float*  lp    = (float*)(ws + 41943040);       // 2x4096x16 f32 = 524,288
  ushort* ao_hi = (ushort*)(ws + 42467328);      // 10,485,760
  ushort* ao_lo = (ushort*)(ws + 52953088);      // ends 63,438,848 (spills into dead Qb head)
  size_t o = 62914560;
  ushort* xhi = (ushort*)(ws + o);               // 10.5 MB
  ushort* xlo = (ushort*)(ws + o + 10485760);    // 10.5 MB
  ushort* Qb  = (ushort*)(ws + o);               // alias x-region after gemm1 (12.58 MB)
  o += 20971520;
  ushort* wqT_h = (ushort*)(ws + o);             // 9.83 MB
  ushort* wqT_l = (ushort*)(ws + o + 9830400);   // 9.83 MB
  ushort* Kb    = (ushort*)(ws + o);             // alias wqT after gemm1 (12.58 MB)
  o += 19660800;
  ushort* VbT   = (ushort*)(ws + o); o += 10485760;   // 10.5 MB
  ushort* wpT_h = (ushort*)(ws + o); o += 3276800;
  ushort* wpT_l = (ushort*)(ws + o);             // total 120,586,240 B (same as R3/R4)

  // 1) split inputs / weights
  split_rows<<<SEQ * HIDDEN / 1024, 256, 0, stream>>>(x, xhi, xlo, SEQ * HIDDEN);
  split_T<<<dim3(QKV_N / 32, HIDDEN / 32), 256, 0, stream>>>(w_qkv, wqT_h, wqT_l, HIDDEN, QKV_N);
  split_T<<<dim3(HIDDEN / 32, HIDDEN / 32), 256, 0, stream>>>(w_proj, wpT_h, wpT_l, HIDDEN, HIDDEN);
  // 2) qkv = x @ w_qkv + b_qkv   (split-bf16 MFMA, ~fp32 accurate)
  gemm_bt_split<<<dim3(QKV_N / 128, SEQ / 128), 256, 0, stream>>>(
      xhi, xlo, wqT_h, wqT_l, b_qkv, qkv, SEQ, QKV_N, HIDDEN);
  // 3) rotary -> Qb/Kb; V transpose -> VbT  (qkv dead afterwards)
  rotary_qk<<<SEQ * NH * 48 / 256, 256, 0, stream>>>(qkv, cosb, sinb, Qb, Kb);
  v_trans<<<dim3(SEQ / 64, NH), 256, 0, stream>>>(qkv, VbT);
  // 4) attention partials (K-split x2, barrier-free) -> Op/lp over dead qkv
  attn_mfma<<<dim3(SEQ / 128, NH, 2), 256, 0, stream>>>(Qb, Kb, VbT, Op, lp);
  // 5) merge halves, normalize, split bf16 -> ao_hi/ao_lo
  merge_split<<<SEQ * HIDDEN / 1024, 256, 0, stream>>>(Op, lp, ao_hi, ao_lo);
  // 6) out = attn @ w_proj + b_proj
  gemm_bt_split<<<dim3(HIDDEN / 128, SEQ / 128), 256, 0, stream>>>(
      ao_hi, ao_lo, wpT_h, wpT_l, b_proj, out, SEQ, HIDDEN, HIDDEN);
}

// Round 6
// 426.747 us; speedup vs baseline: 1.3255x; 1.3255x over previous
//
#include <hip/hip_runtime.h>
#include <hip/hip_bf16.h>

#define SEQ 4096
#define HIDDEN 1280
#define NH 16
#define HD 80
#define QKV_N 3840
#define INV_SCALE 0.11180339887498949f
#define LOG2E 1.4426950408889634f

typedef __attribute__((ext_vector_type(8))) short bf16x8;
typedef __attribute__((ext_vector_type(4))) float f32x4;

__device__ __forceinline__ ushort f2bf(float f) {
  union { float f; unsigned u; } v; v.f = f;
  unsigned u = v.u;
  u += 0x7fff + ((u >> 16) & 1);   // RTNE
  return (ushort)(u >> 16);
}
__device__ __forceinline__ float bf2f(ushort h) {
  union { unsigned u; float f; } v; v.u = ((unsigned)h) << 16;
  return v.f;
}
__device__ __forceinline__ unsigned pk_bf16(float a, float b) {
  union { __hip_bfloat162 h; unsigned u; } v;
  v.h = __float22bfloat162_rn(make_float2(a, b));
  return v.u;
}
// async global->LDS, 16B per lane. LDS side must be base + lane*16 contiguous.
__device__ __forceinline__ void async16(void* lds, const void* g) {
  __builtin_amdgcn_global_load_lds(
      (const __attribute__((address_space(1))) unsigned*)g,
      (__attribute__((address_space(3))) unsigned*)(unsigned)(size_t)lds,
      16, 0, 0);
}

// -------- split fp32 -> bf16 hi (+optional lo), elementwise --------
__global__ __launch_bounds__(256)
void split_rows(const float* __restrict__ A, ushort* __restrict__ hi,
                ushort* __restrict__ lo, int n) {
  int i = (blockIdx.x * 256 + threadIdx.x) * 4;
  if (i >= n) return;
  float4 v = *(const float4*)&A[i];
  ushort h[4], l[4];
  float x[4] = {v.x, v.y, v.z, v.w};
#pragma unroll
  for (int t = 0; t < 4; ++t) {
    h[t] = f2bf(x[t]);
    l[t] = f2bf(x[t] - bf2f(h[t]));
  }
  *(ushort4*)&hi[i] = *(ushort4*)h;
  if (lo) *(ushort4*)&lo[i] = *(ushort4*)l;
}

// ---- split + transpose: W[K][N] -> hiT (+optional loT) [N][K] ----
__global__ __launch_bounds__(256)
void split_T(const float* __restrict__ W, ushort* __restrict__ hiT,
             ushort* __restrict__ loT, int K, int N) {
  __shared__ float T[32][33];
  const int k0 = blockIdx.y * 32, n0 = blockIdx.x * 32;
  for (int e = threadIdx.x; e < 1024; e += 256) {
    int r = e >> 5, c = e & 31;
    T[r][c] = W[(size_t)(k0 + r) * N + n0 + c];
  }
  __syncthreads();
  for (int e = threadIdx.x; e < 1024; e += 256) {
    int r = e >> 5, c = e & 31;        // r: n-index, c: k-index
    float x = T[c][r];
    ushort h = f2bf(x);
    size_t idx = (size_t)(n0 + r) * K + k0 + c;
    hiT[idx] = h;
    if (loT) loT[idx] = f2bf(x - bf2f(h));
  }
}

// ------- pure-bf16 GEMM: C[M,N] = A[M,K] @ B^T[N,K] + bias -------
// 128x128 tile, BK=64 (two 32-chunks), 4 waves (64x64 each), 32 MFMA/iter.
__global__ __launch_bounds__(256)
void gemm_bt_bf16(const ushort* __restrict__ Ab, const ushort* __restrict__ Bb,
                  const float* __restrict__ bias, float* __restrict__ C,
                  int M, int N, int K) {
  __shared__ __align__(16) ushort lds[16384];   // A0|A1|B0|B1 tiles, 8KB each
  const int tid = threadIdx.x, lane = tid & 63, w = tid >> 6;
  const int m15 = lane & 15, g = lane >> 4;
  const int m0 = blockIdx.y * 128, n0 = blockIdx.x * 128;
  const int wm = (w & 1) * 64, wn = (w >> 1) * 64;

  // wave w stages region w: 0:A cols[k0,k0+32) 1:A[k0+32,k0+64) 2:B0 3:B1
  const ushort* stage_base =
      (w < 2) ? Ab + (size_t)m0 * K + (w & 1) * 32
              : Bb + (size_t)n0 * K + (w & 1) * 32;
  char* ldsb = (char*)lds;

  f32x4 acc[4][4];
#pragma unroll
  for (int i = 0; i < 4; ++i)
#pragma unroll
    for (int j = 0; j < 4; ++j) acc[i][j] = (f32x4){0.f, 0.f, 0.f, 0.f};

  for (int k0 = 0; k0 < K; k0 += 64) {
    __syncthreads();
#pragma unroll
    for (int i = 0; i < 8; ++i) {
      int o = i * 1024 + lane * 16;      // byte offset within 8KB region
      int row = o >> 6, colb = o & 63;   // 64 B per row (32 bf16)
      async16(ldsb + w * 8192 + o,
              (const char*)(stage_base + (size_t)row * K + k0) + colb);
    }
    __syncthreads();
    bf16x8 ah[4][2], bh[4][2];
#pragma unroll
    for (int t = 0; t < 4; ++t) {
      ah[t][0] = *(const bf16x8*)&lds[(wm + t * 16 + m15) * 32 + g * 8];
      ah[t][1] = *(const bf16x8*)&lds[4096 + (wm + t * 16 + m15) * 32 + g * 8];
      bh[t][0] = *(const bf16x8*)&lds[8192 + (wn + t * 16 + m15) * 32 + g * 8];
      bh[t][1] = *(const bf16x8*)&lds[12288 + (wn + t * 16 + m15) * 32 + g * 8];
    }
#pragma unroll
    for (int mi = 0; mi < 4; ++mi)
#pragma unroll
      for (int ni = 0; ni < 4; ++ni) {
        acc[mi][ni] = __builtin_amdgcn_mfma_f32_16x16x32_bf16(ah[mi][0], bh[ni][0], acc[mi][ni], 0, 0, 0);
        acc[mi][ni] = __builtin_amdgcn_mfma_f32_16x16x32_bf16(ah[mi][1], bh[ni][1], acc[mi][ni], 0, 0, 0);
      }
  }
#pragma unroll
  for (int mi = 0; mi < 4; ++mi)
#pragma unroll
    for (int ni = 0; ni < 4; ++ni) {
      int col = n0 + wn + ni * 16 + m15;
      float bv = bias[col];
#pragma unroll
      for (int r = 0; r < 4; ++r)
        C[(size_t)(m0 + wm + mi * 16 + g * 4 + r) * N + col] = acc[mi][ni][r] + bv;
    }
}

// ------- split-bf16 GEMM: C[M,N] = (Ah+Al)[M,K] @ (Bh+Bl)^T[N,K] + bias -------
__global__ __launch_bounds__(256)
void gemm_bt_split(const ushort* __restrict__ Ah, const ushort* __restrict__ Al,
                   const ushort* __restrict__ Bh, const ushort* __restrict__ Bl,
                   const float* __restrict__ bias, float* __restrict__ C,
                   int M, int N, int K) {
  __shared__ __align__(16) ushort lds[16384];   // Ah|Al|Bh|Bl tiles, 8KB each
  const int tid = threadIdx.x, lane = tid & 63, w = tid >> 6;
  const int m15 = lane & 15, g = lane >> 4;
  const int m0 = blockIdx.y * 128, n0 = blockIdx.x * 128;
  const int wm = (w & 1) * 64, wn = (w >> 1) * 64;

  const ushort* stage_base =
      (w == 0) ? Ah + (size_t)m0 * K :
      (w == 1) ? Al + (size_t)m0 * K :
      (w == 2) ? Bh + (size_t)n0 * K : Bl + (size_t)n0 * K;
  char* ldsb = (char*)lds;

  f32x4 acc[4][4];
#pragma unroll
  for (int i = 0; i < 4; ++i)
#pragma unroll
    for (int j = 0; j < 4; ++j) acc[i][j] = (f32x4){0.f, 0.f, 0.f, 0.f};

  for (int k0 = 0; k0 < K; k0 += 32) {
    __syncthreads();
#pragma unroll
    for (int i = 0; i < 8; ++i) {
      int o = i * 1024 + lane * 16;
      int row = o >> 6, colb = o & 63;
      async16(ldsb + w * 8192 + o,
              (const char*)(stage_base + (size_t)row * K + k0) + colb);
    }
    __syncthreads();
    bf16x8 ah[4], al[4], bh[4], bl[4];
#pragma unroll
    for (int t = 0; t < 4; ++t) {
      ah[t] = *(const bf16x8*)&lds[(wm + t * 16 + m15) * 32 + g * 8];
      al[t] = *(const bf16x8*)&lds[4096 + (wm + t * 16 + m15) * 32 + g * 8];
      bh[t] = *(const bf16x8*)&lds[8192 + (wn + t * 16 + m15) * 32 + g * 8];
      bl[t] = *(const bf16x8*)&lds[12288 + (wn + t * 16 + m15) * 32 + g * 8];
    }
#pragma unroll
    for (int mi = 0; mi < 4; ++mi)
#pragma unroll
      for (int ni = 0; ni < 4; ++ni) {
        acc[mi][ni] = __builtin_amdgcn_mfma_f32_16x16x32_bf16(ah[mi], bh[ni], acc[mi][ni], 0, 0, 0);
        acc[mi][ni] = __builtin_amdgcn_mfma_f32_16x16x32_bf16(ah[mi], bl[ni], acc[mi][ni], 0, 0, 0);
        acc[mi][ni] = __builtin_amdgcn_mfma_f32_16x16x32_bf16(al[mi], bh[ni], acc[mi][ni], 0, 0, 0);
      }
  }
#pragma unroll
  for (int mi = 0; mi < 4; ++mi)
#pragma unroll
    for (int ni = 0; ni < 4; ++ni) {
      int col = n0 + wn + ni * 16 + m15;
      float bv = bias[col];
#pragma unroll
      for (int r = 0; r < 4; ++r)
        C[(size_t)(m0 + wm + mi * 16 + g * 4 + r) * N + col] = acc[mi][ni][r] + bv;
    }
}

// ------------- rotary + cast: Qb/Kb [h][s][96] (zero-padded) -------------
__global__ __launch_bounds__(256)
void rotary_qk(const float* __restrict__ qkv, const float* __restrict__ cosb,
               const float* __restrict__ sinb, ushort* __restrict__ Qb,
               ushort* __restrict__ Kb) {
  int id = blockIdx.x * 256 + threadIdx.x;
  int j = id % 48;
  int h = (id / 48) % NH;
  int s = id / (48 * NH);
  size_t qrow = (size_t)((h << 12) + s) * 96;
  if (j < 40) {
    size_t base = (size_t)s * QKV_N + h * HD;
    float c1 = cosb[s * HD + j],      s1 = sinb[s * HD + j];
    float c2 = cosb[s * HD + j + 40], s2 = sinb[s * HD + j + 40];
    const float QS = INV_SCALE * LOG2E;
    float q1 = qkv[base + j], q2 = qkv[base + j + 40];
    Qb[qrow + j]      = f2bf((q1 * c1 - q2 * s1) * QS);
    Qb[qrow + j + 40] = f2bf((q2 * c2 + q1 * s2) * QS);
    float k1 = qkv[base + HIDDEN + j], k2 = qkv[base + HIDDEN + j + 40];
    Kb[qrow + j]      = f2bf(k1 * c1 - k2 * s1);
    Kb[qrow + j + 40] = f2bf(k2 * c2 + k1 * s2);
  } else {
    int d = 80 + (j - 40) * 2;
    Qb[qrow + d] = 0; Qb[qrow + d + 1] = 0;
    Kb[qrow + d] = 0; Kb[qrow + d + 1] = 0;
  }
}

// ------------- V transpose: qkv v-section -> VbT[h][80][4096] bf16 -------------
__global__ __launch_bounds__(256)
void v_trans(const float* __restrict__ qkv, ushort* __restrict__ VbT) {
  __shared__ float T[64][81];
  const int h = blockIdx.y, s0 = blockIdx.x * 64;
  for (int e = threadIdx.x; e < 5120; e += 256) {
    int r = e / 80, d = e % 80;
    T[r][d] = qkv[(size_t)(s0 + r) * QKV_N + 2 * HIDDEN + h * HD + d];
  }
  __syncthreads();
  for (int e = threadIdx.x; e < 2560; e += 256) {
    int d = e >> 5, rp = (e & 31) * 2;
    ushort2 p;
    p.x = f2bf(T[rp][d]);
    p.y = f2bf(T[rp + 1][d]);
    *(ushort2*)&VbT[(size_t)h * 80 * SEQ + (size_t)d * SEQ + s0 + rp] = p;
  }
}

// ---- flash attention, bf16 MFMA, fixed-max softmax, LDS-staged, K-split x2 ----
// grid (SEQ/128, NH, 2), 256 threads (4 waves x 32 q-rows). R4 staging structure
// (global_load_lds for K, padded LDS for V^T) -- shared across waves; z halves
// the key range for occupancy (LDS 47.5KB -> 3 blocks/CU).
// Emits unnormalized O (fp32) + l partials; merge_split combines.
#define LPS 88    // Ps row stride (ushort)
#define LVS 72    // Vt row stride (ushort)
__global__ __launch_bounds__(256)
void attn_mfma(const ushort* __restrict__ Qb, const ushort* __restrict__ Kb,
               const ushort* __restrict__ VbT, float* __restrict__ Op,
               float* __restrict__ lp) {
  // [0,24576): Qs 128x96 (contig) -> reused as Ps[128][LPS]
  // [24576,36864): Ks 64x96 (contig, global_load_lds)
  // [36864,48384): Vt 80x[LVS]
  __shared__ __align__(16) ushort lds[24192];
  ushort* Ps = lds;
  ushort* Ks = lds + 12288;
  ushort* Vt = lds + 18432;
  char* ldsb = (char*)lds;

  const int tid = threadIdx.x, lane = tid & 63, w = tid >> 6;
  const int m15 = lane & 15, g = lane >> 4;
  const int h = blockIdx.y, q0 = blockIdx.x * 128, half = blockIdx.z;
  const size_t hq = (size_t)h * SEQ * 96;
  const char* Qg = (const char*)Qb + (hq + (size_t)q0 * 96) * 2;
  const char* Kg = (const char*)Kb + hq * 2;
  const ushort* Vg = VbT + (size_t)h * 80 * SEQ;

  // ---- stage Q tile (24576 B contiguous)
#pragma unroll
  for (int i = 0; i < 6; ++i) {
    int o = (w + i * 4) * 1024 + lane * 16;
    async16(ldsb + o, Qg + o);
  }
  __syncthreads();
  bf16x8 qf[2][3];   // B-operand: n = q = w*32+mi*16+m15
#pragma unroll
  for (int mi = 0; mi < 2; ++mi)
#pragma unroll
    for (int c = 0; c < 3; ++c)
      qf[mi][c] = *(const bf16x8*)&lds[(w * 32 + mi * 16 + m15) * 96 + c * 32 + g * 8];
  __syncthreads();   // all qf reads drained before anyone overwrites Qs (as Ps)

  f32x4 o_[2][5];
#pragma unroll
  for (int mi = 0; mi < 2; ++mi)
#pragma unroll
    for (int n = 0; n < 5; ++n) o_[mi][n] = (f32x4){0.f, 0.f, 0.f, 0.f};
  float l_part[2] = {0.f, 0.f};

  for (int kt = 0; kt < SEQ / 128; ++kt) {
    const int kbase = half * (SEQ / 2) + kt * 64;
    __syncthreads();   // prior iter's Ks/Vt/Ps reads done
    // ---- stage K (12288 B contiguous)
#pragma unroll
    for (int i = 0; i < 3; ++i) {
      int o = (w + i * 4) * 1024 + lane * 16;
      async16(ldsb + 24576 + o, Kg + (size_t)kbase * 192 + o);
    }
    // ---- stage V^T (80 rows x 128 B)
#pragma unroll
    for (int i = 0; i < 3; ++i) {
      int c = tid + i * 256;
      if (c < 640) {
        int d = c >> 3, cg = c & 7;
        float4 t = *(const float4*)&Vg[(size_t)d * SEQ + kbase + cg * 8];
        *(float4*)&Vt[d * LVS + cg * 8] = t;
      }
    }
    __syncthreads();
    // ---- S^T = K Q^T (log2-scaled): rows=key, col=q
    f32x4 st[2][4];
#pragma unroll
    for (int mi = 0; mi < 2; ++mi)
#pragma unroll
      for (int j = 0; j < 4; ++j) st[mi][j] = (f32x4){0.f, 0.f, 0.f, 0.f};
#pragma unroll
    for (int j = 0; j < 4; ++j)
#pragma unroll
      for (int c = 0; c < 3; ++c) {
        bf16x8 kf = *(const bf16x8*)&Ks[(j * 16 + m15) * 96 + c * 32 + g * 8];
        st[0][j] = __builtin_amdgcn_mfma_f32_16x16x32_bf16(kf, qf[0][c], st[0][j], 0, 0, 0);
        st[1][j] = __builtin_amdgcn_mfma_f32_16x16x32_bf16(kf, qf[1][c], st[1][j], 0, 0, 0);
      }
    // ---- p = exp2(s); accumulate l per-lane; pack & store P^T -> Ps[q][key]
#pragma unroll
    for (int mi = 0; mi < 2; ++mi) {
      float ls = 0.f;
#pragma unroll
      for (int j = 0; j < 4; ++j) {
        float p0 = __builtin_amdgcn_exp2f(st[mi][j][0]);
        float p1 = __builtin_amdgcn_exp2f(st[mi][j][1]);
        float p2 = __builtin_amdgcn_exp2f(st[mi][j][2]);
        float p3 = __builtin_amdgcn_exp2f(st[mi][j][3]);
        ls += (p0 + p1) + (p2 + p3);
        uint2 pw;
        pw.x = pk_bf16(p0, p1);
        pw.y = pk_bf16(p2, p3);
        *(uint2*)&Ps[(w * 32 + mi * 16 + m15) * LPS + j * 16 + g * 4] = pw;
      }
      l_part[mi] += ls;
    }
    // Ps rows are wave-private; order LDS writes before cross-lane reads.
    asm volatile("s_waitcnt lgkmcnt(0)" ::: "memory");
    // ---- O += P V
#pragma unroll
    for (int kc = 0; kc < 2; ++kc) {
      bf16x8 pf0 = *(const bf16x8*)&Ps[(w * 32 + m15) * LPS + kc * 32 + g * 8];
      bf16x8 pf1 = *(const bf16x8*)&Ps[(w * 32 + 16 + m15) * LPS + kc * 32 + g * 8];
#pragma unroll
      for (int n = 0; n < 5; ++n) {
        bf16x8 vf = *(const bf16x8*)&Vt[(n * 16 + m15) * LVS + kc * 32 + g * 8];
        o_[0][n] = __builtin_amdgcn_mfma_f32_16x16x32_bf16(pf0, vf, o_[0][n], 0, 0, 0);
        o_[1][n] = __builtin_amdgcn_mfma_f32_16x16x32_bf16(pf1, vf, o_[1][n], 0, 0, 0);
      }
    }
  }
  // ---- l partials: reduce over g-groups; lane m15 holds q=m15's sum
  float l_red[2];
#pragma unroll
  for (int mi = 0; mi < 2; ++mi) {
    float t = l_part[mi];
    t += __shfl_xor(t, 16);
    t += __shfl_xor(t, 32);
    l_red[mi] = t;
  }
  if (g == 0) {
    lp[(size_t)half * SEQ * NH + (size_t)(q0 + w * 32 + m15) * NH + h] = l_red[0];
    lp[(size_t)half * SEQ * NH + (size_t)(q0 + w * 32 + 16 + m15) * NH + h] = l_red[1];
  }
  // ---- unnormalized O partial
  float* Oph = Op + (size_t)half * SEQ * HIDDEN;
#pragma unroll
  for (int mi = 0; mi < 2; ++mi)
#pragma unroll
    for (int r = 0; r < 4; ++r) {
      int grow = q0 + w * 32 + mi * 16 + g * 4 + r;
#pragma unroll
      for (int n = 0; n < 5; ++n)
        Oph[(size_t)grow * HIDDEN + h * HD + n * 16 + m15] = o_[mi][n][r];
    }
}

// -------- merge halves + normalize + split to bf16 hi/lo for proj GEMM --------
__global__ __launch_bounds__(256)
void merge_split(const float* __restrict__ Op, const float* __restrict__ lp,
                 ushort* __restrict__ ao_hi, ushort* __restrict__ ao_lo) {
  int id = blockIdx.x * 256 + threadIdx.x;
  int i4 = id * 4;                          // SEQ*HIDDEN/4 threads
  int s = i4 / HIDDEN, col = i4 % HIDDEN, hh = col / HD;
  float4 a = *(const float4*)&Op[i4];
  float4 b = *(const float4*)&Op[(size_t)SEQ * HIDDEN + i4];
  float l = lp[s * NH + hh] + lp[SEQ * NH + s * NH + hh];
  float inv = 1.f / l;
  float x[4] = {(a.x + b.x) * inv, (a.y + b.y) * inv,
                (a.z + b.z) * inv, (a.w + b.w) * inv};
  ushort h[4], lo[4];
#pragma unroll
  for (int t = 0; t < 4; ++t) {
    h[t] = f2bf(x[t]);
    lo[t] = f2bf(x[t] - bf2f(h[t]));
  }
  *(ushort4*)&ao_hi[i4] = *(ushort4*)h;
  *(ushort4*)&ao_lo[i4] = *(ushort4*)lo;
}

extern "C" void kernel_launch(void* const* d_in, const int* in_sizes, int n_in,
                              void* d_out, int out_size, void* d_ws, size_t ws_size,
                              hipStream_t stream) {
  const float* x      = (const float*)d_in[0];
  const float* cosb   = (const float*)d_in[1];
  const float* sinb   = (const float*)d_in[2];
  const float* w_qkv  = (const float*)d_in[3];
  const float* b_qkv  = (const float*)d_in[4];
  const float* w_proj = (const float*)d_in[5];
  const float* b_proj = (const float*)d_in[6];
  float* out = (float*)d_out;

  // workspace layout (aliased; all kernels strictly ordered on `stream`):
  char* ws = (char*)d_ws;
  float*  qkv   = (float*)ws;                    // 60 MB; dead after v_trans
  float*  Op    = (float*)ws;                    // 2x4096x1280 f32 = 41,943,040
  float*  lp    = (float*)(ws + 41943040);       // 2x4096x16 f32 = 524,288
  ushort* ao_hi = (ushort*)(ws + 42467328);      // 10,485,760
  ushort* ao_lo = (ushort*)(ws + 52953088);      // ends 63,438,848 (dead-Qb head)
  size_t o = 62914560;
  ushort* xhi = (ushort*)(ws + o);               // 10.5 MB (hi only; no lo needed)
  ushort* Qb  = (ushort*)(ws + o);               // alias x-region after gemm1
  o += 20971520;
  ushort* wqT_h = (ushort*)(ws + o);             // 9.83 MB (hi only)
  ushort* Kb    = (ushort*)(ws + o);             // alias wqT after gemm1
  o += 19660800;
  ushort* VbT   = (ushort*)(ws + o); o += 10485760;   // 10.5 MB
  ushort* wpT_h = (ushort*)(ws + o); o += 3276800;
  ushort* wpT_l = (ushort*)(ws + o);             // total ~120.6 MB

  // 1) casts / splits
  split_rows<<<SEQ * HIDDEN / 1024, 256, 0, stream>>>(x, xhi, nullptr, SEQ * HIDDEN);
  split_T<<<dim3(QKV_N / 32, HIDDEN / 32), 256, 0, stream>>>(w_qkv, wqT_h, nullptr, HIDDEN, QKV_N);
  split_T<<<dim3(HIDDEN / 32, HIDDEN / 32), 256, 0, stream>>>(w_proj, wpT_h, wpT_l, HIDDEN, HIDDEN);
  // 2) qkv = x @ w_qkv + b_qkv   (pure bf16 MFMA; consumers re-cast to bf16 anyway)
  gemm_bt_bf16<<<dim3(QKV_N / 128, SEQ / 128), 256, 0, stream>>>(
      xhi, wqT_h, b_qkv, qkv, SEQ, QKV_N, HIDDEN);
  // 3) rotary -> Qb/Kb; V transpose -> VbT  (qkv dead afterwards)
  rotary_qk<<<SEQ * NH * 48 / 256, 256, 0, stream>>>(qkv, cosb, sinb, Qb, Kb);
  v_trans<<<dim3(SEQ / 64, NH), 256, 0, stream>>>(qkv, VbT);
  // 4) attention partials (LDS-staged, K-split x2) -> Op/lp over dead qkv
  attn_mfma<<<dim3(SEQ / 128, NH, 2), 256, 0, stream>>>(Qb, Kb, VbT, Op, lp);
  // 5) merge halves, normalize, split bf16 -> ao_hi/ao_lo
  merge_split<<<SEQ * HIDDEN / 1024, 256, 0, stream>>>(Op, lp, ao_hi, ao_lo);
  // 6) out = attn @ w_proj + b_proj  (split-bf16, fp32-grade)
  gemm_bt_split<<<dim3(HIDDEN / 128, SEQ / 128), 256, 0, stream>>>(
      ao_hi, ao_lo, wpT_h, wpT_l, b_proj, out, SEQ, HIDDEN, HIDDEN);
}